// Round 11
// baseline (14.385 us; speedup 1.0000x reference)
//
#include <hip/hip_runtime.h>
#include <math.h>

#define D 256
#define NC 8
#define G 16
#define MINS 10
#define NBH 64            // scanner blocks (compile-time for unrolled reduce)
#define MAGIC0 0x5A17C0DE
#define MAGIC1 0x0DDBA11F

// ---- workspace layout (bytes) ----
#define OFF_FLAGS   0u                     // NBH*2 ints (512B)
#define OFF_HIST    4096u                  // NBH*G ints (4KB)
#define OFF_NZH     8192u                  // NBH*G ints (4KB)
#define OFF_IDX     12288u                 // n ints (256KB)

__device__ __forceinline__ int group_of(int t, int b) {
    t = t < 0 ? 0 : (t > NC - 1 ? NC - 1 : t);
    return b * NC + t;
}

// packed-lower-triangle row offset, rows padded to 4 floats (33280 floats total)
__device__ __forceinline__ int rowoff(int i) {
    int q = i >> 2, s = i & 3;
    return 4 * (2 * q * (q + 1) + s * (q + 1));
}

// 16x16 diag-block factor on lanes/tids 0-15 (register rows, shfl broadcasts).
__device__ __forceinline__ void factor_diag(
    float* T, float (*L11c)[16], float* invdb, int kb16, int lane, float& plog) {
    const int r = kb16 + lane;
    float rr[16];
    const float* Tr = T + rowoff(r);
    #pragma unroll
    for (int q = 0; q < 4; ++q) {
        if (kb16 + q * 4 <= r) {
            float4 v = *(const float4*)(Tr + kb16 + q * 4);
            rr[q*4+0] = v.x; rr[q*4+1] = v.y; rr[q*4+2] = v.z; rr[q*4+3] = v.w;
        } else {
            rr[q*4+0] = 0.0f; rr[q*4+1] = 0.0f; rr[q*4+2] = 0.0f; rr[q*4+3] = 0.0f;
        }
    }
    float mypiv = 1.0f, myinv = 1.0f;
    #pragma unroll
    for (int pc = 0; pc < 16; ++pc) {
        const float piv = __shfl(rr[pc], pc);
        const float inv = 1.0f / sqrtf(piv);
        mypiv = (lane == pc) ? piv : mypiv;
        myinv = (lane == pc) ? inv : myinv;
        if (lane > pc) rr[pc] *= inv;
        #pragma unroll
        for (int j = pc + 1; j < 16; ++j) {
            const float Lj = __shfl(rr[pc], j);
            if (lane >= j) rr[j] = fmaf(-rr[pc], Lj, rr[j]);
        }
    }
    plog += __logf(mypiv);
    invdb[lane] = myinv;
    #pragma unroll
    for (int pp = 0; pp < 16; ++pp)
        if (pp < lane) L11c[pp][lane] = rr[pp];
}

// ---- single kernel: 64 scanner blocks; block 0 additionally decides. ----
// Scan: per-block group-count + sampled nz-lower-bound histograms (ballot,
// no atomics). nz lower bound: rows with (i&3)==0 whose first-16B sumsq
// >= 1e-24 (=> ||row|| >= 1e-12 => contributes 1 to tr(G)); sound since
// nz_total >= nz_sampled.
// Handshake: hist rows -> threadfence -> 2-word constant flag. Poison (0xAA)
// never matches; stale flags from a prior replay are safe because hist values
// are pure functions of the unmutated inputs (a racing rewrite stores
// identical bytes).
// Decide (block 0): cert per group: logdet(aG+(1+eps)I) >= log(1 + a*nz_lb);
// deficit==0 when a*nz_lb >= 512 (2x margin over exact threshold 255).
// Fast path: out=0. Fallback (exact, deterministic, serial per needy group):
// collect indices -> in-LDS gram (packed triangle) -> blocked Cholesky.
__global__ __launch_bounds__(256) void k_all(
    const float* __restrict__ feat, const int* __restrict__ target,
    const int* __restrict__ batch,
    int* __restrict__ hist, int* __restrict__ nzhist, int* __restrict__ flags,
    int* __restrict__ idxbuf, float* __restrict__ out, int n, int cpb, int chunks) {
    __shared__ float T[33280];          // 130 KB triangle (+ scan/hist scratch)
    __shared__ float Zt[256][20];       // 20 KB transposed chunk / reused as PT
    __shared__ float L11c[2][16][16];
    __shared__ float invdb[2][16];
    __shared__ int scnt[G], sneed[G];
    __shared__ float gdef[G];
    __shared__ int wb[4], wcs[4];
    __shared__ int cursor, tctr;
    const int tid = threadIdx.x;
    const int wave = tid >> 6, lane = tid & 63;
    const int b = blockIdx.x;

    // ================= phase 1: scan my slice =================
    {
        int* sc = (int*)T;              // [4][G]
        int* sn = sc + 4 * G;           // [4][G]
        int myc = 0, mynz = 0;
        const int c0 = b * cpb;
        const int c1 = min(c0 + cpb, chunks);
        for (int c = c0; c < c1; ++c) {
            const int i = c * 256 + tid;
            const bool valid = i < n;
            const int g = valid ? group_of(target[i], batch[i]) : -1;
            bool nz = false;
            if (valid && ((i & 3) == 0)) {
                const float4 v = *(const float4*)(feat + (size_t)i * D);
                const float s = v.x*v.x + v.y*v.y + v.z*v.z + v.w*v.w;
                nz = (s >= 1e-24f);
            }
            #pragma unroll
            for (int gv = 0; gv < G; ++gv) {
                unsigned long long m  = __ballot(g == gv);
                unsigned long long mz = __ballot(g == gv && nz);
                if (lane == gv) { myc += __popcll(m); mynz += __popcll(mz); }
            }
        }
        if (lane < G) { sc[wave * G + lane] = myc; sn[wave * G + lane] = mynz; }
        __syncthreads();
        if (tid < G) {
            hist[b * G + tid]   = sc[0*G+tid] + sc[1*G+tid] + sc[2*G+tid] + sc[3*G+tid];
            nzhist[b * G + tid] = sn[0*G+tid] + sn[1*G+tid] + sn[2*G+tid] + sn[3*G+tid];
        }
        __syncthreads();
        if (tid == 0) {
            __threadfence();
            volatile int* vf = (volatile int*)flags;
            vf[2 * b]     = MAGIC0;
            vf[2 * b + 1] = MAGIC1;
        }
    }
    if (b != 0) return;

    // ================= phase 2 (block 0): wait for all scanners =================
    {
        volatile int* vf = (volatile int*)flags;
        if (tid < NBH - 1) {
            const int p = tid + 1;
            while (vf[2 * p] != MAGIC0 || vf[2 * p + 1] != MAGIC1) { }
        }
        __syncthreads();
        __threadfence();
    }

    // ---- reduce histograms, evaluate certificates ----
    {
        int* hh = (int*)T;              // NBH*G ints
        int* hz = hh + NBH * G;         // 8 KB total, fits in T
        for (int e = tid; e < NBH * G; e += 256) { hh[e] = hist[e]; hz[e] = nzhist[e]; }
        __syncthreads();
        if (tid < G) {
            int run = 0, nz = 0;
            #pragma unroll
            for (int bb = 0; bb < NBH; ++bb) { run += hh[bb * G + tid]; nz += hz[bb * G + tid]; }
            scnt[tid] = run;
            const float nn = fmaxf((float)run, 1.0f);
            const float aa = (float)D / (nn * 0.04f);       // D/(n*eps^2)
            // groups below MINS never enter the loss -> no fallback needed
            sneed[tid] = (run >= MINS && aa * (float)nz < 512.0f) ? 1 : 0;
            gdef[tid] = 0.0f;
        }
        __syncthreads();
    }
    int anyf = 0;
    #pragma unroll
    for (int gv = 0; gv < G; ++gv) anyf |= sneed[gv];   // uniform (LDS)
    if (!anyf) {
        // all contributing groups certified: every deficit is exactly 0
        if (tid == 0) out[0] = 0.0f;
        return;
    }

    // ================= fallback: serial over needy groups =================
    for (int g = 0; g < G; ++g) {
        if (!sneed[g]) continue;
        const int ng = scnt[g];

        // ---- A: collect this group's row indices (ballot rank, deterministic) ----
        if (tid == 0) cursor = 0;
        __syncthreads();
        for (int base = 0; base < n; base += 256) {
            const int i = base + tid;
            const bool mine = (i < n) && (group_of(target[i], batch[i]) == g);
            unsigned long long m = __ballot(mine);
            const int rank = __popcll(m & ((1ull << lane) - 1ull));
            if (lane == 0) wcs[wave] = __popcll(m);
            __syncthreads();
            if (tid == 0) {
                int r = cursor;
                #pragma unroll
                for (int w = 0; w < 4; ++w) { wb[w] = r; r += wcs[w]; }
                cursor = r;
            }
            __syncthreads();
            if (mine) idxbuf[wb[wave] + rank] = i;
        }
        __syncthreads();

        // ---- B: zero packed triangle ----
        for (int e = tid; e < 33280; e += 256) T[e] = 0.0f;

        // ---- C: gram accumulation, 16-row chunks, normalize on the fly ----
        const int rs = tid >> 4, sg = tid & 15;   // 16 threads per staged row
        for (int c0 = 0; c0 < ng; c0 += 16) {
            float vals[16];
            float s = 0.0f;
            const int rloc = c0 + rs;
            if (rloc < ng) {
                const int row = idxbuf[rloc];
                const float* fp = feat + (size_t)row * D + sg * 16;
                const float4 a = *(const float4*)fp;
                const float4 bb = *(const float4*)(fp + 4);
                const float4 cc = *(const float4*)(fp + 8);
                const float4 dd = *(const float4*)(fp + 12);
                vals[0]=a.x; vals[1]=a.y; vals[2]=a.z; vals[3]=a.w;
                vals[4]=bb.x; vals[5]=bb.y; vals[6]=bb.z; vals[7]=bb.w;
                vals[8]=cc.x; vals[9]=cc.y; vals[10]=cc.z; vals[11]=cc.w;
                vals[12]=dd.x; vals[13]=dd.y; vals[14]=dd.z; vals[15]=dd.w;
                #pragma unroll
                for (int q = 0; q < 16; ++q) s = fmaf(vals[q], vals[q], s);
            } else {
                #pragma unroll
                for (int q = 0; q < 16; ++q) vals[q] = 0.0f;
            }
            #pragma unroll
            for (int d2 = 8; d2; d2 >>= 1) s += __shfl_xor(s, d2, 64);
            const float inv = 1.0f / fmaxf(sqrtf(s), 1e-12f);
            __syncthreads();     // prev chunk's reads of Zt done
            #pragma unroll
            for (int q = 0; q < 16; ++q) Zt[sg * 16 + q][rs] = vals[q] * inv;
            __syncthreads();

            // lower-triangle 4x4 blocks: 64 block-rows -> 2080 blocks
            for (int bidx = tid; bidx < 2080; bidx += 256) {
                int br = 0;
                while ((br + 1) * (br + 2) / 2 <= bidx) ++br;
                const int bc = bidx - br * (br + 1) / 2;
                float acc[4][4];
                #pragma unroll
                for (int i2 = 0; i2 < 4; ++i2)
                    #pragma unroll
                    for (int j = 0; j < 4; ++j) acc[i2][j] = 0.0f;
                #pragma unroll 4
                for (int k = 0; k < 16; ++k) {
                    const float a0 = Zt[br*4+0][k], a1 = Zt[br*4+1][k];
                    const float a2 = Zt[br*4+2][k], a3 = Zt[br*4+3][k];
                    const float b0 = Zt[bc*4+0][k], b1 = Zt[bc*4+1][k];
                    const float b2 = Zt[bc*4+2][k], b3 = Zt[bc*4+3][k];
                    acc[0][0]=fmaf(a0,b0,acc[0][0]); acc[0][1]=fmaf(a0,b1,acc[0][1]);
                    acc[0][2]=fmaf(a0,b2,acc[0][2]); acc[0][3]=fmaf(a0,b3,acc[0][3]);
                    acc[1][0]=fmaf(a1,b0,acc[1][0]); acc[1][1]=fmaf(a1,b1,acc[1][1]);
                    acc[1][2]=fmaf(a1,b2,acc[1][2]); acc[1][3]=fmaf(a1,b3,acc[1][3]);
                    acc[2][0]=fmaf(a2,b0,acc[2][0]); acc[2][1]=fmaf(a2,b1,acc[2][1]);
                    acc[2][2]=fmaf(a2,b2,acc[2][2]); acc[2][3]=fmaf(a2,b3,acc[2][3]);
                    acc[3][0]=fmaf(a3,b0,acc[3][0]); acc[3][1]=fmaf(a3,b1,acc[3][1]);
                    acc[3][2]=fmaf(a3,b2,acc[3][2]); acc[3][3]=fmaf(a3,b3,acc[3][3]);
                }
                #pragma unroll
                for (int i2 = 0; i2 < 4; ++i2) {
                    const int r = br * 4 + i2;
                    float* Tr = T + rowoff(r) + bc * 4;
                    if (bc < br) {
                        Tr[0] += acc[i2][0]; Tr[1] += acc[i2][1];
                        Tr[2] += acc[i2][2]; Tr[3] += acc[i2][3];
                    } else {
                        #pragma unroll
                        for (int j = 0; j < 4; ++j)
                            if (bc * 4 + j <= r) Tr[j] += acc[i2][j];
                    }
                }
            }
        }
        __syncthreads();

        // ---- D: M = aa*gram + (1+1e-6) I ----
        {
            const float nn = fmaxf((float)ng, 1.0f);
            const float aa = (float)D / (nn * 0.04f);
            for (int e = tid; e < 33280; e += 256) T[e] *= aa;
            __syncthreads();
            if (tid < 256) T[rowoff(tid) + tid] += 1.0f + 1e-6f;
            __syncthreads();
        }

        // ---- E: blocked Cholesky in LDS (BK=16), logdet = sum log(pivots) ----
        float* PT = &Zt[0][0];       // 16*256 floats, reuses Zt
        float plog = 0.0f;
        const int li = lane >> 3, lj = lane & 7;

        if (tid < 16) factor_diag(T, L11c[0], invdb[0], 0, tid, plog);
        __syncthreads();

        for (int kb = 0; kb < 15; ++kb) {
            const int kb16 = kb * 16;
            const int par = kb & 1;
            const int pstart = kb16 + 16;
            const int R = 256 - pstart;

            if (tid < R) {
                const int r = pstart + tid;
                const float* Tr = T + rowoff(r) + kb16;
                float x[16];
                {
                    float4 v0 = *(const float4*)(Tr + 0);
                    float4 v1 = *(const float4*)(Tr + 4);
                    float4 v2 = *(const float4*)(Tr + 8);
                    float4 v3 = *(const float4*)(Tr + 12);
                    x[0]=v0.x; x[1]=v0.y; x[2]=v0.z; x[3]=v0.w;
                    x[4]=v1.x; x[5]=v1.y; x[6]=v1.z; x[7]=v1.w;
                    x[8]=v2.x; x[9]=v2.y; x[10]=v2.z; x[11]=v2.w;
                    x[12]=v3.x; x[13]=v3.y; x[14]=v3.z; x[15]=v3.w;
                }
                float iv[16];
                {
                    const float* ivp = invdb[par];
                    float4 i0 = *(const float4*)(ivp + 0);
                    float4 i1 = *(const float4*)(ivp + 4);
                    float4 i2 = *(const float4*)(ivp + 8);
                    float4 i3 = *(const float4*)(ivp + 12);
                    iv[0]=i0.x; iv[1]=i0.y; iv[2]=i0.z; iv[3]=i0.w;
                    iv[4]=i1.x; iv[5]=i1.y; iv[6]=i1.z; iv[7]=i1.w;
                    iv[8]=i2.x; iv[9]=i2.y; iv[10]=i2.z; iv[11]=i2.w;
                    iv[12]=i3.x; iv[13]=i3.y; iv[14]=i3.z; iv[15]=i3.w;
                }
                const float (*Lc)[16] = L11c[par];
                float4 n0 = *(const float4*)&Lc[0][0];
                float4 n1 = *(const float4*)&Lc[0][4];
                float4 n2 = *(const float4*)&Lc[0][8];
                float4 n3 = *(const float4*)&Lc[0][12];
                #pragma unroll
                for (int c = 0; c < 16; ++c) {
                    const float col[16] = {n0.x,n0.y,n0.z,n0.w, n1.x,n1.y,n1.z,n1.w,
                                           n2.x,n2.y,n2.z,n2.w, n3.x,n3.y,n3.z,n3.w};
                    if (c < 15) {
                        n0 = *(const float4*)&Lc[c+1][0];
                        n1 = *(const float4*)&Lc[c+1][4];
                        n2 = *(const float4*)&Lc[c+1][8];
                        n3 = *(const float4*)&Lc[c+1][12];
                    }
                    const float xc = x[c] * iv[c];
                    x[c] = xc;
                    #pragma unroll
                    for (int j = 0; j < 16; ++j)
                        if (j > c) x[j] = fmaf(-xc, col[j], x[j]);
                }
                #pragma unroll
                for (int pp = 0; pp < 16; ++pp)
                    PT[pp * 256 + r] = x[pp];
            }
            if (tid == 0) tctr = 1;
            __syncthreads();

            const int MRm = (R + 31) >> 5;
            const int nmac = MRm * (MRm + 1) / 2;

            auto do_tile = [&](int idx) {
                int MI = 0, base = 0;
                while (base + MI + 1 <= idx) { base += MI + 1; ++MI; }
                const int MJ = idx - base;
                const int r0 = pstart + MI * 32 + li * 4;
                const int c0 = pstart + MJ * 32 + lj * 4;
                if (r0 >= 256 || c0 >= 256) return;
                if (c0 > r0 + 3) return;
                float acc[4][4];
                #pragma unroll
                for (int qi = 0; qi < 4; ++qi)
                    #pragma unroll
                    for (int qj = 0; qj < 4; ++qj) acc[qi][qj] = 0.0f;
                #pragma unroll
                for (int pq = 0; pq < 4; ++pq) {
                    float4 a[4], bb[4];
                    #pragma unroll
                    for (int q = 0; q < 4; ++q) {
                        a[q]  = *(const float4*)&PT[(pq * 4 + q) * 256 + r0];
                        bb[q] = *(const float4*)&PT[(pq * 4 + q) * 256 + c0];
                    }
                    #pragma unroll
                    for (int q = 0; q < 4; ++q) {
                        float a4[4] = {a[q].x, a[q].y, a[q].z, a[q].w};
                        float b4[4] = {bb[q].x, bb[q].y, bb[q].z, bb[q].w};
                        #pragma unroll
                        for (int qi = 0; qi < 4; ++qi)
                            #pragma unroll
                            for (int qj = 0; qj < 4; ++qj)
                                acc[qi][qj] = fmaf(a4[qi], b4[qj], acc[qi][qj]);
                    }
                }
                #pragma unroll
                for (int qi = 0; qi < 4; ++qi) {
                    const int r = r0 + qi;
                    float* cp = T + rowoff(r) + c0;
                    if (c0 + 3 <= r) {
                        float4 t = *(float4*)cp;
                        t.x -= acc[qi][0]; t.y -= acc[qi][1];
                        t.z -= acc[qi][2]; t.w -= acc[qi][3];
                        *(float4*)cp = t;
                    } else {
                        #pragma unroll
                        for (int qj = 0; qj < 4; ++qj)
                            if (c0 + qj <= r) cp[qj] -= acc[qi][qj];
                    }
                }
            };

            if (wave == 0) {
                do_tile(0);   // contains next diag block
                if (lane < 16)
                    factor_diag(T, L11c[par ^ 1], invdb[par ^ 1], pstart, lane, plog);
            }
            int grab;
            if (lane == 0) grab = atomicAdd(&tctr, 1);
            grab = __shfl(grab, 0);
            while (grab < nmac) {
                do_tile(grab);
                if (lane == 0) grab = atomicAdd(&tctr, 1);
                grab = __shfl(grab, 0);
            }
            __syncthreads();
        }

        if (tid < 16) {
            #pragma unroll
            for (int d = 8; d; d >>= 1) plog += __shfl_xor(plog, d);
            if (tid == 0) {
                const float nn = fmaxf((float)ng, 1.0f);
                const float logdet = plog + (nn - (float)D) * logf(1.0f + 1e-6f + 1e-12f);
                gdef[g] = fmaxf(0.5f * logf(256.0f) - 0.5f * logdet, 0.0f);
            }
        }
        __syncthreads();
    }

    // ---- final combine ----
    if (tid == 0) {
        float s[2] = {0.0f, 0.0f}, c2[2] = {0.0f, 0.0f};
        for (int g = 0; g < G; ++g) {
            if (scnt[g] < MINS) continue;
            s[g / NC] += gdef[g]; c2[g / NC] += 1.0f;
        }
        float avg = 0.0f;
        for (int bq = 0; bq < 2; ++bq)
            avg += (c2[bq] > 0.0f) ? s[bq] / fmaxf(c2[bq], 1.0f) : 0.0f;
        out[0] = 0.05f * 0.5f * avg;            // loss_weight*lambda*mean over B=2
    }
}

extern "C" void kernel_launch(void* const* d_in, const int* in_sizes, int n_in,
                              void* d_out, int out_size, void* d_ws, size_t ws_size,
                              hipStream_t stream) {
    const int*   target = (const int*)d_in[1];
    const float* feat   = (const float*)d_in[2];
    const int*   batch  = (const int*)d_in[3];
    float* out = (float*)d_out;
    char* ws = (char*)d_ws;
    const int n = in_sizes[1];

    int* flags  = (int*)(ws + OFF_FLAGS);
    int* hist   = (int*)(ws + OFF_HIST);
    int* nzhist = (int*)(ws + OFF_NZH);
    int* idxbuf = (int*)(ws + OFF_IDX);

    const int chunks = (n + 255) / 256;
    const int cpb    = (chunks + NBH - 1) / NBH;

    k_all<<<NBH, 256, 0, stream>>>(feat, target, batch, hist, nzhist, flags,
                                   idxbuf, out, n, cpb, chunks);
}

// Round 12
// 12.272 us; speedup vs baseline: 1.1722x; 1.1722x over previous
//
#include <hip/hip_runtime.h>
#include <math.h>

#define D 256
#define NC 8
#define G 16
#define MINS 10
#define NBH 64            // cert blocks (compile-time for K2's unrolled scan)

// ---- workspace layout (bytes) ----
#define OFF_HIST    0u                     // NBH*G ints (4KB)
#define OFF_NZH     4096u                  // NBH*G ints (4KB)
#define OFF_IDX     8192u                  // n ints (256KB)

__device__ __forceinline__ int group_of(int t, int b) {
    t = t < 0 ? 0 : (t > NC - 1 ? NC - 1 : t);
    return b * NC + t;
}

// ---- K1: per-block group-count + sampled nz-lower-bound histograms ----
// nz lower bound: rows with (i&3)==0 whose first-16B sumsq >= 1e-24
// (=> ||row|| >= 1e-12 => contributes 1 to tr(G)). Sound: nz_total >= nz_sampled.
// thread-per-row, ballot histogram, no atomics.
__global__ __launch_bounds__(256) void k_cert(
    const float* __restrict__ feat, const int* __restrict__ target,
    const int* __restrict__ batch,
    int* __restrict__ hist, int* __restrict__ nzhist, int n, int cpb, int chunks) {
    __shared__ int sc[4][G], sn[4][G];
    const int tid = threadIdx.x;
    const int wave = tid >> 6, lane = tid & 63;
    int myc = 0, mynz = 0;
    const int c0 = blockIdx.x * cpb;
    const int c1 = min(c0 + cpb, chunks);
    for (int c = c0; c < c1; ++c) {
        const int i = c * 256 + tid;
        const bool valid = i < n;
        const int g = valid ? group_of(target[i], batch[i]) : -1;
        bool nz = false;
        if (valid && ((i & 3) == 0)) {
            const float4 v = *(const float4*)(feat + (size_t)i * D);
            const float s = v.x*v.x + v.y*v.y + v.z*v.z + v.w*v.w;
            nz = (s >= 1e-24f);
        }
        #pragma unroll
        for (int gv = 0; gv < G; ++gv) {
            unsigned long long m  = __ballot(g == gv);
            unsigned long long mz = __ballot(g == gv && nz);
            if (lane == gv) { myc += __popcll(m); mynz += __popcll(mz); }
        }
    }
    if (lane < G) { sc[wave][lane] = myc; sn[wave][lane] = mynz; }
    __syncthreads();
    if (tid < G) {
        hist[blockIdx.x * G + tid]   = sc[0][tid] + sc[1][tid] + sc[2][tid] + sc[3][tid];
        nzhist[blockIdx.x * G + tid] = sn[0][tid] + sn[1][tid] + sn[2][tid] + sn[3][tid];
    }
}

// packed-lower-triangle row offset, rows padded to 4 floats (33280 floats total)
__device__ __forceinline__ int rowoff(int i) {
    int q = i >> 2, s = i & 3;
    return 4 * (2 * q * (q + 1) + s * (q + 1));
}

// 16x16 diag-block factor on lanes/tids 0-15 (register rows, shfl broadcasts).
__device__ __forceinline__ void factor_diag(
    float* T, float (*L11c)[16], float* invdb, int kb16, int lane, float& plog) {
    const int r = kb16 + lane;
    float rr[16];
    const float* Tr = T + rowoff(r);
    #pragma unroll
    for (int q = 0; q < 4; ++q) {
        if (kb16 + q * 4 <= r) {
            float4 v = *(const float4*)(Tr + kb16 + q * 4);
            rr[q*4+0] = v.x; rr[q*4+1] = v.y; rr[q*4+2] = v.z; rr[q*4+3] = v.w;
        } else {
            rr[q*4+0] = 0.0f; rr[q*4+1] = 0.0f; rr[q*4+2] = 0.0f; rr[q*4+3] = 0.0f;
        }
    }
    float mypiv = 1.0f, myinv = 1.0f;
    #pragma unroll
    for (int pc = 0; pc < 16; ++pc) {
        const float piv = __shfl(rr[pc], pc);
        const float inv = 1.0f / sqrtf(piv);
        mypiv = (lane == pc) ? piv : mypiv;
        myinv = (lane == pc) ? inv : myinv;
        if (lane > pc) rr[pc] *= inv;
        #pragma unroll
        for (int j = pc + 1; j < 16; ++j) {
            const float Lj = __shfl(rr[pc], j);
            if (lane >= j) rr[j] = fmaf(-rr[pc], Lj, rr[j]);
        }
    }
    plog += __logf(mypiv);
    invdb[lane] = myinv;
    #pragma unroll
    for (int pp = 0; pp < 16; ++pp)
        if (pp < lane) L11c[pp][lane] = rr[pp];
}

// ---- K2: single decider block. Reduces histograms, evaluates the certificate
// per group (cert: logdet(aG+(1+eps)I) >= log(1 + a*nz_lb); deficit==0 when
// a*nz_lb >= 512, 2x margin over exact threshold 255). Fast path: out = 0.
// Fallback (exact, deterministic, serial per needy group in this one block):
// collect indices -> in-LDS gram (packed triangle) -> blocked Cholesky.
__global__ __launch_bounds__(256) void k_decide(
    const float* __restrict__ feat, const int* __restrict__ target,
    const int* __restrict__ batch,
    const int* __restrict__ hist, const int* __restrict__ nzhist,
    int* __restrict__ idxbuf, float* __restrict__ out, int n) {
    __shared__ float T[33280];          // 130 KB packed lower triangle (+hist scratch)
    __shared__ float Zt[256][20];       // 20 KB transposed chunk / reused as PT
    __shared__ float L11c[2][16][16];
    __shared__ float invdb[2][16];
    __shared__ int scnt[G], sneed[G];
    __shared__ float gdef[G];
    __shared__ int wb[4], wcs[4];
    __shared__ int cursor, tctr;
    const int tid = threadIdx.x;
    const int wave = tid >> 6, lane = tid & 63;

    // ---- step 1: counts / need per group from histograms ----
    {
        int* hh = (int*)T;              // NBH*G ints
        int* hz = hh + NBH * G;         // 8 KB total, fits in T
        for (int e = tid; e < NBH * G; e += 256) { hh[e] = hist[e]; hz[e] = nzhist[e]; }
        __syncthreads();
        if (tid < G) {
            int run = 0, nz = 0;
            #pragma unroll
            for (int b = 0; b < NBH; ++b) { run += hh[b * G + tid]; nz += hz[b * G + tid]; }
            scnt[tid] = run;
            const float nn = fmaxf((float)run, 1.0f);
            const float aa = (float)D / (nn * 0.04f);       // D/(n*eps^2)
            // groups below MINS never enter the loss -> no fallback needed
            sneed[tid] = (run >= MINS && aa * (float)nz < 512.0f) ? 1 : 0;
            gdef[tid] = 0.0f;
        }
        __syncthreads();
    }
    int anyf = 0;
    #pragma unroll
    for (int gv = 0; gv < G; ++gv) anyf |= sneed[gv];   // uniform (LDS)
    if (!anyf) {
        // all contributing groups certified: every deficit is exactly 0
        if (tid == 0) out[0] = 0.0f;
        return;
    }

    // ================= fallback: serial over needy groups =================
    for (int g = 0; g < G; ++g) {
        if (!sneed[g]) continue;
        const int ng = scnt[g];

        // ---- A: collect this group's row indices (ballot rank, deterministic) ----
        if (tid == 0) cursor = 0;
        __syncthreads();
        for (int base = 0; base < n; base += 256) {
            const int i = base + tid;
            const bool mine = (i < n) && (group_of(target[i], batch[i]) == g);
            unsigned long long m = __ballot(mine);
            const int rank = __popcll(m & ((1ull << lane) - 1ull));
            if (lane == 0) wcs[wave] = __popcll(m);
            __syncthreads();
            if (tid == 0) {
                int r = cursor;
                #pragma unroll
                for (int w = 0; w < 4; ++w) { wb[w] = r; r += wcs[w]; }
                cursor = r;
            }
            __syncthreads();
            if (mine) idxbuf[wb[wave] + rank] = i;
        }
        __syncthreads();

        // ---- B: zero packed triangle ----
        for (int e = tid; e < 33280; e += 256) T[e] = 0.0f;

        // ---- C: gram accumulation, 16-row chunks, normalize on the fly ----
        const int rs = tid >> 4, sg = tid & 15;   // 16 threads per staged row
        for (int c0 = 0; c0 < ng; c0 += 16) {
            float vals[16];
            float s = 0.0f;
            const int rloc = c0 + rs;
            if (rloc < ng) {
                const int row = idxbuf[rloc];
                const float* fp = feat + (size_t)row * D + sg * 16;
                const float4 a = *(const float4*)fp;
                const float4 b = *(const float4*)(fp + 4);
                const float4 cc = *(const float4*)(fp + 8);
                const float4 dd = *(const float4*)(fp + 12);
                vals[0]=a.x; vals[1]=a.y; vals[2]=a.z; vals[3]=a.w;
                vals[4]=b.x; vals[5]=b.y; vals[6]=b.z; vals[7]=b.w;
                vals[8]=cc.x; vals[9]=cc.y; vals[10]=cc.z; vals[11]=cc.w;
                vals[12]=dd.x; vals[13]=dd.y; vals[14]=dd.z; vals[15]=dd.w;
                #pragma unroll
                for (int q = 0; q < 16; ++q) s = fmaf(vals[q], vals[q], s);
            } else {
                #pragma unroll
                for (int q = 0; q < 16; ++q) vals[q] = 0.0f;
            }
            #pragma unroll
            for (int d2 = 8; d2; d2 >>= 1) s += __shfl_xor(s, d2, 64);
            const float inv = 1.0f / fmaxf(sqrtf(s), 1e-12f);
            __syncthreads();     // prev chunk's reads of Zt done
            #pragma unroll
            for (int q = 0; q < 16; ++q) Zt[sg * 16 + q][rs] = vals[q] * inv;
            __syncthreads();

            // lower-triangle 4x4 blocks: 64 block-rows -> 2080 blocks
            for (int bidx = tid; bidx < 2080; bidx += 256) {
                int br = 0;
                while ((br + 1) * (br + 2) / 2 <= bidx) ++br;
                const int bc = bidx - br * (br + 1) / 2;
                float acc[4][4];
                #pragma unroll
                for (int i2 = 0; i2 < 4; ++i2)
                    #pragma unroll
                    for (int j = 0; j < 4; ++j) acc[i2][j] = 0.0f;
                #pragma unroll 4
                for (int k = 0; k < 16; ++k) {
                    const float a0 = Zt[br*4+0][k], a1 = Zt[br*4+1][k];
                    const float a2 = Zt[br*4+2][k], a3 = Zt[br*4+3][k];
                    const float b0 = Zt[bc*4+0][k], b1 = Zt[bc*4+1][k];
                    const float b2 = Zt[bc*4+2][k], b3 = Zt[bc*4+3][k];
                    acc[0][0]=fmaf(a0,b0,acc[0][0]); acc[0][1]=fmaf(a0,b1,acc[0][1]);
                    acc[0][2]=fmaf(a0,b2,acc[0][2]); acc[0][3]=fmaf(a0,b3,acc[0][3]);
                    acc[1][0]=fmaf(a1,b0,acc[1][0]); acc[1][1]=fmaf(a1,b1,acc[1][1]);
                    acc[1][2]=fmaf(a1,b2,acc[1][2]); acc[1][3]=fmaf(a1,b3,acc[1][3]);
                    acc[2][0]=fmaf(a2,b0,acc[2][0]); acc[2][1]=fmaf(a2,b1,acc[2][1]);
                    acc[2][2]=fmaf(a2,b2,acc[2][2]); acc[2][3]=fmaf(a2,b3,acc[2][3]);
                    acc[3][0]=fmaf(a3,b0,acc[3][0]); acc[3][1]=fmaf(a3,b1,acc[3][1]);
                    acc[3][2]=fmaf(a3,b2,acc[3][2]); acc[3][3]=fmaf(a3,b3,acc[3][3]);
                }
                #pragma unroll
                for (int i2 = 0; i2 < 4; ++i2) {
                    const int r = br * 4 + i2;
                    float* Tr = T + rowoff(r) + bc * 4;
                    if (bc < br) {
                        Tr[0] += acc[i2][0]; Tr[1] += acc[i2][1];
                        Tr[2] += acc[i2][2]; Tr[3] += acc[i2][3];
                    } else {
                        #pragma unroll
                        for (int j = 0; j < 4; ++j)
                            if (bc * 4 + j <= r) Tr[j] += acc[i2][j];
                    }
                }
            }
        }
        __syncthreads();

        // ---- D: M = aa*gram + (1+1e-6) I ----
        {
            const float nn = fmaxf((float)ng, 1.0f);
            const float aa = (float)D / (nn * 0.04f);
            for (int e = tid; e < 33280; e += 256) T[e] *= aa;
            __syncthreads();
            if (tid < 256) T[rowoff(tid) + tid] += 1.0f + 1e-6f;
            __syncthreads();
        }

        // ---- E: blocked Cholesky in LDS (BK=16), logdet = sum log(pivots) ----
        float* PT = &Zt[0][0];       // 16*256 floats, reuses Zt
        float plog = 0.0f;
        const int li = lane >> 3, lj = lane & 7;

        if (tid < 16) factor_diag(T, L11c[0], invdb[0], 0, tid, plog);
        __syncthreads();

        for (int kb = 0; kb < 15; ++kb) {
            const int kb16 = kb * 16;
            const int par = kb & 1;
            const int pstart = kb16 + 16;
            const int R = 256 - pstart;

            if (tid < R) {
                const int r = pstart + tid;
                const float* Tr = T + rowoff(r) + kb16;
                float x[16];
                {
                    float4 v0 = *(const float4*)(Tr + 0);
                    float4 v1 = *(const float4*)(Tr + 4);
                    float4 v2 = *(const float4*)(Tr + 8);
                    float4 v3 = *(const float4*)(Tr + 12);
                    x[0]=v0.x; x[1]=v0.y; x[2]=v0.z; x[3]=v0.w;
                    x[4]=v1.x; x[5]=v1.y; x[6]=v1.z; x[7]=v1.w;
                    x[8]=v2.x; x[9]=v2.y; x[10]=v2.z; x[11]=v2.w;
                    x[12]=v3.x; x[13]=v3.y; x[14]=v3.z; x[15]=v3.w;
                }
                float iv[16];
                {
                    const float* ivp = invdb[par];
                    float4 i0 = *(const float4*)(ivp + 0);
                    float4 i1 = *(const float4*)(ivp + 4);
                    float4 i2 = *(const float4*)(ivp + 8);
                    float4 i3 = *(const float4*)(ivp + 12);
                    iv[0]=i0.x; iv[1]=i0.y; iv[2]=i0.z; iv[3]=i0.w;
                    iv[4]=i1.x; iv[5]=i1.y; iv[6]=i1.z; iv[7]=i1.w;
                    iv[8]=i2.x; iv[9]=i2.y; iv[10]=i2.z; iv[11]=i2.w;
                    iv[12]=i3.x; iv[13]=i3.y; iv[14]=i3.z; iv[15]=i3.w;
                }
                const float (*Lc)[16] = L11c[par];
                float4 n0 = *(const float4*)&Lc[0][0];
                float4 n1 = *(const float4*)&Lc[0][4];
                float4 n2 = *(const float4*)&Lc[0][8];
                float4 n3 = *(const float4*)&Lc[0][12];
                #pragma unroll
                for (int c = 0; c < 16; ++c) {
                    const float col[16] = {n0.x,n0.y,n0.z,n0.w, n1.x,n1.y,n1.z,n1.w,
                                           n2.x,n2.y,n2.z,n2.w, n3.x,n3.y,n3.z,n3.w};
                    if (c < 15) {
                        n0 = *(const float4*)&Lc[c+1][0];
                        n1 = *(const float4*)&Lc[c+1][4];
                        n2 = *(const float4*)&Lc[c+1][8];
                        n3 = *(const float4*)&Lc[c+1][12];
                    }
                    const float xc = x[c] * iv[c];
                    x[c] = xc;
                    #pragma unroll
                    for (int j = 0; j < 16; ++j)
                        if (j > c) x[j] = fmaf(-xc, col[j], x[j]);
                }
                #pragma unroll
                for (int pp = 0; pp < 16; ++pp)
                    PT[pp * 256 + r] = x[pp];
            }
            if (tid == 0) tctr = 1;
            __syncthreads();

            const int MRm = (R + 31) >> 5;
            const int nmac = MRm * (MRm + 1) / 2;

            auto do_tile = [&](int idx) {
                int MI = 0, base = 0;
                while (base + MI + 1 <= idx) { base += MI + 1; ++MI; }
                const int MJ = idx - base;
                const int r0 = pstart + MI * 32 + li * 4;
                const int c0 = pstart + MJ * 32 + lj * 4;
                if (r0 >= 256 || c0 >= 256) return;
                if (c0 > r0 + 3) return;
                float acc[4][4];
                #pragma unroll
                for (int qi = 0; qi < 4; ++qi)
                    #pragma unroll
                    for (int qj = 0; qj < 4; ++qj) acc[qi][qj] = 0.0f;
                #pragma unroll
                for (int pq = 0; pq < 4; ++pq) {
                    float4 a[4], b[4];
                    #pragma unroll
                    for (int q = 0; q < 4; ++q) {
                        a[q] = *(const float4*)&PT[(pq * 4 + q) * 256 + r0];
                        b[q] = *(const float4*)&PT[(pq * 4 + q) * 256 + c0];
                    }
                    #pragma unroll
                    for (int q = 0; q < 4; ++q) {
                        float a4[4] = {a[q].x, a[q].y, a[q].z, a[q].w};
                        float b4[4] = {b[q].x, b[q].y, b[q].z, b[q].w};
                        #pragma unroll
                        for (int qi = 0; qi < 4; ++qi)
                            #pragma unroll
                            for (int qj = 0; qj < 4; ++qj)
                                acc[qi][qj] = fmaf(a4[qi], b4[qj], acc[qi][qj]);
                    }
                }
                #pragma unroll
                for (int qi = 0; qi < 4; ++qi) {
                    const int r = r0 + qi;
                    float* cp = T + rowoff(r) + c0;
                    if (c0 + 3 <= r) {
                        float4 t = *(float4*)cp;
                        t.x -= acc[qi][0]; t.y -= acc[qi][1];
                        t.z -= acc[qi][2]; t.w -= acc[qi][3];
                        *(float4*)cp = t;
                    } else {
                        #pragma unroll
                        for (int qj = 0; qj < 4; ++qj)
                            if (c0 + qj <= r) cp[qj] -= acc[qi][qj];
                    }
                }
            };

            if (wave == 0) {
                do_tile(0);   // contains next diag block
                if (lane < 16)
                    factor_diag(T, L11c[par ^ 1], invdb[par ^ 1], pstart, lane, plog);
            }
            int grab;
            if (lane == 0) grab = atomicAdd(&tctr, 1);
            grab = __shfl(grab, 0);
            while (grab < nmac) {
                do_tile(grab);
                if (lane == 0) grab = atomicAdd(&tctr, 1);
                grab = __shfl(grab, 0);
            }
            __syncthreads();
        }

        if (tid < 16) {
            #pragma unroll
            for (int d = 8; d; d >>= 1) plog += __shfl_xor(plog, d);
            if (tid == 0) {
                const float nn = fmaxf((float)ng, 1.0f);
                const float logdet = plog + (nn - (float)D) * logf(1.0f + 1e-6f + 1e-12f);
                gdef[g] = fmaxf(0.5f * logf(256.0f) - 0.5f * logdet, 0.0f);
            }
        }
        __syncthreads();
    }

    // ---- final combine ----
    if (tid == 0) {
        float s[2] = {0.0f, 0.0f}, c2[2] = {0.0f, 0.0f};
        for (int g = 0; g < G; ++g) {
            if (scnt[g] < MINS) continue;
            s[g / NC] += gdef[g]; c2[g / NC] += 1.0f;
        }
        float avg = 0.0f;
        for (int b = 0; b < 2; ++b)
            avg += (c2[b] > 0.0f) ? s[b] / fmaxf(c2[b], 1.0f) : 0.0f;
        out[0] = 0.05f * 0.5f * avg;            // loss_weight*lambda*mean over B=2
    }
}

extern "C" void kernel_launch(void* const* d_in, const int* in_sizes, int n_in,
                              void* d_out, int out_size, void* d_ws, size_t ws_size,
                              hipStream_t stream) {
    const int*   target = (const int*)d_in[1];
    const float* feat   = (const float*)d_in[2];
    const int*   batch  = (const int*)d_in[3];
    float* out = (float*)d_out;
    char* ws = (char*)d_ws;
    const int n = in_sizes[1];

    int* hist   = (int*)(ws + OFF_HIST);
    int* nzhist = (int*)(ws + OFF_NZH);
    int* idxbuf = (int*)(ws + OFF_IDX);

    const int chunks = (n + 255) / 256;
    const int cpb    = (chunks + NBH - 1) / NBH;

    k_cert  <<<NBH, 256, 0, stream>>>(feat, target, batch, hist, nzhist, n, cpb, chunks);
    k_decide<<<1, 256, 0, stream>>>(feat, target, batch, hist, nzhist, idxbuf, out, n);
}